// Round 6
// baseline (355.118 us; speedup 1.0000x reference)
//
#include <hip/hip_runtime.h>

#define RADIUS 20
#define KSIZE  41
#define ALPHA_F 50.0f
#define TY     8                    // fused/W: band rows per block
#define WID    512
#define HEI    512
#define PW     (WID + 2 * RADIUS)   // 552 floats per padded row (LDS + intermediate)
#define NRQ    44                   // input rows per 4-output row-quarter (4 + 2*RADIUS)
#define NRH    48                   // input rows per 8-output half-band (8 + 2*RADIUS)
#define PF     8                    // prefetch ring depth (power of 2); PF=4 measured +25us (R3/R4)

typedef float floatx4 __attribute__((ext_vector_type(4)));  // native vec for nt-store

// Normalized Gaussian taps, sigma=5, radius=20: w[t]=exp(-0.5*((t-20)/5)^2)/S,
// S = 12.53263858. Baked literals; fully-unrolled loops fold these to constants.
__device__ constexpr float G[KSIZE] = {
    2.6770e-05f, 5.8390e-05f, 1.22380e-04f, 2.46460e-04f, 4.76840e-04f,
    8.86410e-04f, 1.583160e-03f, 2.716710e-03f, 4.479090e-03f, 7.095210e-03f,
    1.0798630e-02f, 1.5790680e-02f, 2.2185070e-02f, 2.9946720e-02f, 3.8838800e-02f,
    4.8396120e-02f, 5.7940680e-02f, 6.6647650e-02f, 7.3657040e-02f, 7.8211730e-02f,
    7.9791720e-02f,
    7.8211730e-02f, 7.3657040e-02f, 6.6647650e-02f, 5.7940680e-02f, 4.8396120e-02f,
    3.8838800e-02f, 2.9946720e-02f, 2.2185070e-02f, 1.5790680e-02f, 1.0798630e-02f,
    7.095210e-03f, 4.479090e-03f, 2.716710e-03f, 1.583160e-03f, 8.86410e-04f,
    4.76840e-04f, 2.46460e-04f, 1.22380e-04f, 5.8390e-05f, 2.6770e-05f
};

__device__ __forceinline__ int refl(int i, int n) {
    // scipy 'reflect' (edge included); exact for i in [-n, 2n-1]
    i = (i < 0) ? (-1 - i) : i;
    i = (i >= n) ? (2 * n - 1 - i) : i;
    return i;
}

// reflect for warp coords; exact for i in [-512, 1023] (we clamp into that range)
__device__ __forceinline__ int refl512(int i) {
    i = (i < 0) ? (-1 - i) : i;
    return (i >= 512) ? (1023 - i) : i;
}

// ---------------- vertical 41-tap blur helpers (ring-prefetched) ----------------
template<bool INTERIOR>
__device__ __forceinline__ void vblur4(const float* __restrict__ src, int ybase,
                                       float acc[4][4]) {
    float ring[PF][4];
    #pragma unroll
    for (int k = 0; k < PF; ++k) {
        const int gy = INTERIOR ? (ybase + k) : refl(ybase + k, HEI);
        const float4 v = *reinterpret_cast<const float4*>(src + (size_t)gy * WID);
        ring[k][0] = v.x; ring[k][1] = v.y; ring[k][2] = v.z; ring[k][3] = v.w;
    }
    #pragma unroll
    for (int r = 0; r < NRQ; ++r) {
        float v[4];
        #pragma unroll
        for (int j = 0; j < 4; ++j) v[j] = ring[r & (PF - 1)][j];   // static after unroll
        if (r + PF < NRQ) {
            const int gy = INTERIOR ? (ybase + r + PF) : refl(ybase + r + PF, HEI);
            const float4 nv = *reinterpret_cast<const float4*>(src + (size_t)gy * WID);
            ring[r & (PF - 1)][0] = nv.x; ring[r & (PF - 1)][1] = nv.y;
            ring[r & (PF - 1)][2] = nv.z; ring[r & (PF - 1)][3] = nv.w;
        }
        #pragma unroll
        for (int o = 0; o < 4; ++o) {
            const int t = r - o;
            if (t >= 0 && t < KSIZE) {
                const float g = G[t];
                #pragma unroll
                for (int j = 0; j < 4; ++j) acc[o][j] = fmaf(g, v[j], acc[o][j]);
            }
        }
    }
}

template<bool INTERIOR>
__device__ __forceinline__ void vblur8(const float* __restrict__ src, int ybase,
                                       float acc[8][4]) {
    float ring[PF][4];
    #pragma unroll
    for (int k = 0; k < PF; ++k) {
        const int gy = INTERIOR ? (ybase + k) : refl(ybase + k, HEI);
        const float4 v = *reinterpret_cast<const float4*>(src + (size_t)gy * WID);
        ring[k][0] = v.x; ring[k][1] = v.y; ring[k][2] = v.z; ring[k][3] = v.w;
    }
    #pragma unroll
    for (int r = 0; r < NRH; ++r) {
        float v[4];
        #pragma unroll
        for (int j = 0; j < 4; ++j) v[j] = ring[r & (PF - 1)][j];   // static after unroll
        if (r + PF < NRH) {
            const int gy = INTERIOR ? (ybase + r + PF) : refl(ybase + r + PF, HEI);
            const float4 nv = *reinterpret_cast<const float4*>(src + (size_t)gy * WID);
            ring[r & (PF - 1)][0] = nv.x; ring[r & (PF - 1)][1] = nv.y;
            ring[r & (PF - 1)][2] = nv.z; ring[r & (PF - 1)][3] = nv.w;
        }
        #pragma unroll
        for (int o = 0; o < 8; ++o) {
            const int t = r - o;
            if (t >= 0 && t < KSIZE) {
                const float g = G[t];
                #pragma unroll
                for (int j = 0; j < 4; ++j) acc[o][j] = fmaf(g, v[j], acc[o][j]);
            }
        }
    }
}

// =======================  SPLIT PATH: kernel V (vertical)  =======================
// Vertical blur of both fields -> padded intermediate vd[f][b][row][PW] in d_ws.
// No LDS, no barrier: latency hidden purely by wave parallelism.
// Block 512 = 128 col-quads x 2 fields x 2 row-halves; 8 rows x 4 cols per thread.
__global__ __launch_bounds__(512) void vblur_kernel(
    const float* __restrict__ rdx, const float* __restrict__ rdy,
    float* __restrict__ vd, int B) {

    const int tid = threadIdx.x;

    int b, band;                        // grid = B * (HEI/16)
    {
        const int L = blockIdx.x;
        if (B == 64) {                  // XCD-affine: 8 whole batches per XCD
            const int xcd = L & 7;
            const int s   = L >> 3;     // 0..255
            b    = xcd * 8 + (s >> 5);
            band = s & 31;
        } else {
            b    = L / (HEI / 16);
            band = L % (HEI / 16);
        }
    }
    const int y0 = band * 16;
    const size_t base = (size_t)b * (HEI * WID);
    const size_t fstride = (size_t)B * HEI * PW;   // floats per field in intermediate

    const int c4 = tid & 127;
    const int f  = (tid >> 7) & 1;      // wave-uniform
    const int h  = tid >> 8;            // wave-uniform
    const int ybase = y0 + 8 * h - RADIUS;

    const float* src = (f ? rdy : rdx) + base + 4 * c4;
    float* dst = vd + (size_t)f * fstride + (size_t)b * HEI * PW;

    float acc[8][4];
    #pragma unroll
    for (int o = 0; o < 8; ++o)
        #pragma unroll
        for (int j = 0; j < 4; ++j) acc[o][j] = 0.f;

    if (ybase >= 0 && ybase + NRH <= HEI) vblur8<true >(src, ybase, acc);
    else                                  vblur8<false>(src, ybase, acc);

    #pragma unroll
    for (int o = 0; o < 8; ++o) {
        const int row = y0 + 8 * h + o;              // global row
        float* rp = dst + (size_t)row * PW;
        float sv[4];
        #pragma unroll
        for (int j = 0; j < 4; ++j) sv[j] = 2.f * acc[o][j] - 1.f;  // affine commutes with blur
        float4 pack;
        pack.x = sv[0]; pack.y = sv[1]; pack.z = sv[2]; pack.w = sv[3];
        *reinterpret_cast<float4*>(rp + RADIUS + 4 * c4) = pack;
        if (c4 < 5) {                                // cols 0..19 reflect to left halo
            #pragma unroll
            for (int j = 0; j < 4; ++j) rp[RADIUS - 1 - (4 * c4 + j)] = sv[j];
        }
        if (c4 >= 123) {                             // cols 492..511 reflect to right halo
            #pragma unroll
            for (int j = 0; j < 4; ++j) rp[RADIUS + 2 * WID - 1 - (4 * c4 + j)] = sv[j];
        }
    }
}

// =======================  SPLIT PATH: kernel W (h-blur + warp)  =======================
// Reads padded intermediate rows straight from global (L1-served: each row's 2.2 KB
// window is read ~10x within the block). No LDS, no barrier.
__global__ __launch_bounds__(512) void warp_kernel(
    const float* __restrict__ xin, const float* __restrict__ vd,
    float* __restrict__ outp, int B) {

    const int tid = threadIdx.x;

    int b, band;                        // grid = B * (HEI/8)
    {
        const int L = blockIdx.x;
        if (B == 64) {
            const int xcd = L & 7;
            const int s   = L >> 3;     // 0..511
            b    = xcd * 8 + (s >> 6);
            band = s & 63;
        } else {
            b    = L / (HEI / TY);
            band = L % (HEI / TY);
        }
    }
    const int y0 = band * TY;
    const size_t base = (size_t)b * (HEI * WID);
    const size_t fstride = (size_t)B * HEI * PW;

    const int c4 = tid & 127;
    const int rg = tid >> 7;            // 0..3 (wave-uniform)
    const float* img = xin + base;
    const float* vbase = vd + (size_t)b * HEI * PW;

    #pragma unroll
    for (int i = 0; i < 2; ++i) {
        const int o  = rg + 4 * i;      // 0..7
        const int gy = y0 + o;

        const float4* rpx = (const float4*)(vbase + (size_t)gy * PW);
        const float4* rpy = (const float4*)(vbase + fstride + (size_t)gy * PW);

        float dxv[4] = {0.f, 0.f, 0.f, 0.f};
        float dyv[4] = {0.f, 0.f, 0.f, 0.f};

        // Element-major FIR: each float4 is consumed by the <=4 taps that touch it.
        #pragma unroll
        for (int q = 0; q < 11; ++q) {
            const float4 vx = rpx[c4 + q];
            const float4 vy = rpy[c4 + q];
            const float ex[4] = {vx.x, vx.y, vx.z, vx.w};
            const float ey[4] = {vy.x, vy.y, vy.z, vy.w};
            #pragma unroll
            for (int e = 0; e < 4; ++e) {
                const int k = 4 * q + e;
                #pragma unroll
                for (int j = 0; j < 4; ++j) {
                    const int t = k - j;
                    if (t >= 0 && t < KSIZE) {
                        const float g = G[t];
                        dxv[j] = fmaf(g, ex[e], dxv[j]);
                        dyv[j] = fmaf(g, ey[e], dyv[j]);
                    }
                }
            }
        }

        float st[4];
        #pragma unroll
        for (int j = 0; j < 4; ++j) {
            const int col = 4 * c4 + j;
            float xx = (float)col + dxv[j] * ALPHA_F;
            float yy = (float)gy  + dyv[j] * ALPHA_F;
            xx = fminf(fmaxf(xx, -511.f), 1022.f);   // keeps refl512 exact, kills NaN/inf
            yy = fminf(fmaxf(yy, -511.f), 1022.f);
            const float x0f = floorf(xx), y0f = floorf(yy);
            const float wx = xx - x0f, wy = yy - y0f;
            const int x0 = (int)x0f, yb = (int)y0f;
            const int x0r = refl512(x0);
            const int x1r = refl512(x0 + 1);
            const int y0r = refl512(yb);
            const int y1r = refl512(yb + 1);

            const float* r0 = img + ((size_t)y0r << 9);
            const float* r1 = img + ((size_t)y1r << 9);
            const float v00 = r0[x0r];
            const float v01 = r0[x1r];
            const float v10 = r1[x0r];
            const float v11 = r1[x1r];

            const float top = fmaf(wx, v01 - v00, v00);   // 3-lerp
            const float bot = fmaf(wx, v11 - v10, v10);
            st[j] = fmaf(wy, bot - top, top);
        }

        floatx4 pack;
        pack.x = st[0]; pack.y = st[1]; pack.z = st[2]; pack.w = st[3];
        __builtin_nontemporal_store(pack,
            reinterpret_cast<floatx4*>(outp + base + (size_t)gy * WID + 4 * c4));
    }
}

// =======================  FALLBACK: fused kernel (R5, proven)  =======================
__global__ __launch_bounds__(512, 4) void elastic_kernel(
    const float* __restrict__ xin, const float* __restrict__ rdx,
    const float* __restrict__ rdy, float* __restrict__ outp, int B) {

    __shared__ float sdx[TY][PW];
    __shared__ float sdy[TY][PW];

    const int tid = threadIdx.x;

    int b, band;
    {
        const int L = blockIdx.x;
        if (B == 64) {
            const int xcd = L & 7;
            const int s   = L >> 3;
            b    = xcd * 8 + (s >> 6);
            band = s & 63;
        } else {
            b    = L / (HEI / TY);
            band = L % (HEI / TY);
        }
    }
    const int y0 = band * TY;
    const size_t base = (size_t)b * (HEI * WID);

    {
        const int c4 = tid & 127;
        const int f  = (tid >> 7) & 1;
        const int rq = tid >> 8;
        const int ybase = y0 + 4 * rq - RADIUS;

        const float* src = (f ? rdy : rdx) + base + 4 * c4;
        float (*sd)[PW] = f ? sdy : sdx;

        float acc[4][4];
        #pragma unroll
        for (int o = 0; o < 4; ++o)
            #pragma unroll
            for (int j = 0; j < 4; ++j) acc[o][j] = 0.f;

        if (ybase >= 0 && ybase + NRQ <= HEI) vblur4<true >(src, ybase, acc);
        else                                  vblur4<false>(src, ybase, acc);

        #pragma unroll
        for (int o = 0; o < 4; ++o) {
            const int row = 4 * rq + o;
            float sv[4];
            #pragma unroll
            for (int j = 0; j < 4; ++j) sv[j] = 2.f * acc[o][j] - 1.f;
            float4 pack;
            pack.x = sv[0]; pack.y = sv[1]; pack.z = sv[2]; pack.w = sv[3];
            *reinterpret_cast<float4*>(&sd[row][RADIUS + 4 * c4]) = pack;
            if (c4 < 5) {
                #pragma unroll
                for (int j = 0; j < 4; ++j) sd[row][RADIUS - 1 - (4 * c4 + j)] = sv[j];
            }
            if (c4 >= 123) {
                #pragma unroll
                for (int j = 0; j < 4; ++j) sd[row][RADIUS + 2 * WID - 1 - (4 * c4 + j)] = sv[j];
            }
        }
    }
    __syncthreads();

    const int c4 = tid & 127;
    const int rg = tid >> 7;
    const float* img = xin + base;

    #pragma unroll
    for (int i = 0; i < 2; ++i) {
        const int o  = rg + 4 * i;
        const int gy = y0 + o;

        float dxv[4] = {0.f, 0.f, 0.f, 0.f};
        float dyv[4] = {0.f, 0.f, 0.f, 0.f};

        const float4* rpx = (const float4*)(&sdx[o][0]);
        const float4* rpy = (const float4*)(&sdy[o][0]);
        #pragma unroll
        for (int q = 0; q < 11; ++q) {
            const float4 vx = rpx[c4 + q];
            const float4 vy = rpy[c4 + q];
            const float ex[4] = {vx.x, vx.y, vx.z, vx.w};
            const float ey[4] = {vy.x, vy.y, vy.z, vy.w};
            #pragma unroll
            for (int e = 0; e < 4; ++e) {
                const int k = 4 * q + e;
                #pragma unroll
                for (int j = 0; j < 4; ++j) {
                    const int t = k - j;
                    if (t >= 0 && t < KSIZE) {
                        const float g = G[t];
                        dxv[j] = fmaf(g, ex[e], dxv[j]);
                        dyv[j] = fmaf(g, ey[e], dyv[j]);
                    }
                }
            }
        }

        float st[4];
        #pragma unroll
        for (int j = 0; j < 4; ++j) {
            const int col = 4 * c4 + j;
            float xx = (float)col + dxv[j] * ALPHA_F;
            float yy = (float)gy  + dyv[j] * ALPHA_F;
            xx = fminf(fmaxf(xx, -511.f), 1022.f);
            yy = fminf(fmaxf(yy, -511.f), 1022.f);
            const float x0f = floorf(xx), y0f = floorf(yy);
            const float wx = xx - x0f, wy = yy - y0f;
            const int x0 = (int)x0f, yb = (int)y0f;
            const int x0r = refl512(x0);
            const int x1r = refl512(x0 + 1);
            const int y0r = refl512(yb);
            const int y1r = refl512(yb + 1);

            const float* r0 = img + ((size_t)y0r << 9);
            const float* r1 = img + ((size_t)y1r << 9);
            const float v00 = r0[x0r];
            const float v01 = r0[x1r];
            const float v10 = r1[x0r];
            const float v11 = r1[x1r];

            const float top = fmaf(wx, v01 - v00, v00);
            const float bot = fmaf(wx, v11 - v10, v10);
            st[j] = fmaf(wy, bot - top, top);
        }

        floatx4 pack;
        pack.x = st[0]; pack.y = st[1]; pack.z = st[2]; pack.w = st[3];
        __builtin_nontemporal_store(pack,
            reinterpret_cast<floatx4*>(outp + base + (size_t)gy * WID + 4 * c4));
    }
}

extern "C" void kernel_launch(void* const* d_in, const int* in_sizes, int n_in,
                              void* d_out, int out_size, void* d_ws, size_t ws_size,
                              hipStream_t stream) {
    const float* x   = (const float*)d_in[0];
    const float* rdx = (const float*)d_in[1];
    const float* rdy = (const float*)d_in[2];
    float* out = (float*)d_out;

    const int B = in_sizes[1] / (HEI * WID);   // 64

    const size_t need = (size_t)2 * B * HEI * PW * sizeof(float);   // 144.7 MB for B=64
    if (d_ws != nullptr && ws_size >= need) {
        // barrier-free two-kernel pipeline through workspace
        vblur_kernel<<<B * (HEI / 16), 512, 0, stream>>>(rdx, rdy, (float*)d_ws, B);
        warp_kernel <<<B * (HEI / TY), 512, 0, stream>>>(x, (const float*)d_ws, out, B);
    } else {
        elastic_kernel<<<B * (HEI / TY), 512, 0, stream>>>(x, rdx, rdy, out, B);
    }
    (void)n_in; (void)out_size;
}